// Round 3
// baseline (542.425 us; speedup 1.0000x reference)
//
#include <hip/hip_runtime.h>

typedef unsigned short ushort_t;
typedef unsigned int uint_t;

typedef __attribute__((ext_vector_type(8))) __bf16 bf16x8;
typedef __attribute__((ext_vector_type(4))) float f32x4;

#define HH 192
#define WW 192
#define HWD (192*192)          // 36864
#define CC 64
#define BB 16

__device__ __forceinline__ float b2f(uint_t u) {
    return __uint_as_float((u & 0xffffu) << 16);
}
__device__ __forceinline__ ushort_t f2b(float f) {
    uint_t x = __float_as_uint(f);
    uint_t r = x + 0x7fffu + ((x >> 16) & 1u);   // RNE fp32 -> bf16
    return (ushort_t)(r >> 16);
}
__device__ __forceinline__ bf16x8 zero8() {
    uint4 z; z.x = 0; z.y = 0; z.z = 0; z.w = 0;
    return __builtin_bit_cast(bf16x8, z);
}
__device__ __forceinline__ bf16x8 ld8(const ushort_t* p) {
    return __builtin_bit_cast(bf16x8, *(const uint4*)p);
}

// ---------------- kernel 1: Wc[co][ci][u][v] fp32 -> wt[t][co][ci] bf16
__global__ void k_prep(const float* __restrict__ Wc, ushort_t* __restrict__ wt) {
    int i = blockIdx.x * 256 + threadIdx.x;
    if (i < 9 * 64 * 64) {
        int t  = i >> 12;
        int co = (i >> 6) & 63;
        int ci = i & 63;
        wt[i] = f2b(Wc[(co * 64 + ci) * 9 + t]);
    }
}

// ---------------- kernel 2: pooled[b][c] = mean over H*W (fp32)
__global__ void k_pool(const float* __restrict__ x, float* __restrict__ pooled) {
    int c = blockIdx.x, b = blockIdx.y, tid = threadIdx.x;
    const float4* xp = (const float4*)(x + (size_t)(b * 64 + c) * HWD);
    float s = 0.f;
    for (int i = tid; i < HWD / 4; i += 256) {
        float4 u = xp[i];
        s += u.x + u.y + u.z + u.w;
    }
    __shared__ float red[4];
    for (int o = 32; o > 0; o >>= 1) s += __shfl_down(s, o, 64);
    if ((tid & 63) == 0) red[tid >> 6] = s;
    __syncthreads();
    if (tid == 0) pooled[b * 64 + c] = (red[0] + red[1] + red[2] + red[3]) * (1.f / (float)HWD);
}

// ---------------- kernel 3: MLP + channel filter norm -> cf[b][c][t] fp32
__global__ void k_mlp(const float* __restrict__ pooled,
                      const float* __restrict__ W1, const float* __restrict__ b1,
                      const float* __restrict__ W2, const float* __restrict__ b2,
                      const float* __restrict__ std_ch, float* __restrict__ cf) {
    int b = blockIdx.x, tid = threadIdx.x;  // 64 threads
    __shared__ float pl[64], hv[12];
    pl[tid] = pooled[b * 64 + tid];
    __syncthreads();
    if (tid < 12) {
        float h = b1[tid];
        for (int c = 0; c < 64; c++) h += pl[c] * W1[tid * 64 + c];
        hv[tid] = h > 0.f ? h : 0.f;
    }
    __syncthreads();
    int c = tid;
    float r[9]; float m = 0.f;
    #pragma unroll
    for (int t = 0; t < 9; t++) {
        float v = b2[c * 9 + t];
        #pragma unroll
        for (int k = 0; k < 12; k++) v += hv[k] * W2[(c * 9 + t) * 12 + k];
        r[t] = v; m += v;
    }
    m *= (1.f / 9.f);
    float var = 0.f;
    #pragma unroll
    for (int t = 0; t < 9; t++) { float d = r[t] - m; var += d * d; }
    var *= (1.f / 8.f);                     // ddof=1
    float inv = 1.f / (sqrtf(var) + 1e-10f);
    #pragma unroll
    for (int t = 0; t < 9; t++)
        cf[(b * 64 + c) * 9 + t] = (r[t] - m) * inv * std_ch[c * 9 + t];
}

// ---------------- kernel 4: FUSED sf + DDF + leaky -> y NHWC bf16
// Phase 3 v2: pair-parity unroll (no cndmask) + rolling 3x3 window registers
//   (1 new LDS dword per row per 2 outputs instead of 6 per output)
__global__ __launch_bounds__(256, 2)
void k_fused(const float* __restrict__ x, const float* __restrict__ Ws,
             const float* __restrict__ bs, const float* __restrict__ cf,
             ushort_t* __restrict__ y) {
    __shared__ ushort_t xt[64 * 434];      // 55.5 KB
    __shared__ float sfL[256 * 12];        // 12.3 KB
    __shared__ float WsL[576];
    __shared__ float cfL[576];
    __shared__ float bsL[9];

    int b = blockIdx.y;
    int tw = blockIdx.x % 3, th = blockIdx.x / 3;
    int h0 = th * 4, w0 = tw * 64;
    int tid = threadIdx.x;

    for (int i = tid; i < 576; i += 256) { WsL[i] = Ws[i]; cfL[i] = cf[b * 576 + i]; }
    if (tid < 9) bsL[tid] = bs[tid];

    // ---- phase 1: stage x tile (+halo) as bf16 into LDS
    const float* xb = x + (size_t)b * 64 * HWD;
    #pragma unroll
    for (int j = 0; j < 27; j++) {
        int idx = tid + j * 256;           // [0, 6912)
        int c = idx / 108;
        int rem = idx - c * 108;
        int r = rem / 18, seg = rem - r * 18;
        int gr = h0 - 1 + r;
        int gw0 = w0 - 4 + seg * 4;        // float4-aligned; fully in or out of [0,192)
        float4 v;
        if (gr >= 0 && gr < HH && gw0 >= 0 && gw0 < WW)
            v = *(const float4*)(xb + (size_t)c * HWD + (size_t)gr * WW + gw0);
        else { v.x = 0.f; v.y = 0.f; v.z = 0.f; v.w = 0.f; }
        int o = c * 434 + r * 72 + seg * 4;         // even -> 4B aligned
        *(uint_t*)(&xt[o])     = (uint_t)f2b(v.x) | ((uint_t)f2b(v.y) << 16);
        *(uint_t*)(&xt[o + 2]) = (uint_t)f2b(v.z) | ((uint_t)f2b(v.w) << 16);
    }
    __syncthreads();

    // ---- phase 2: spatial filter for own pixel
    {
        int hl = tid >> 6, wl = tid & 63;
        float s[9];
        #pragma unroll
        for (int t = 0; t < 9; t++) s[t] = bsL[t];
        int base = (hl + 1) * 72 + wl + 4;          // center pixel in halo coords
        for (int c = 0; c < 64; c++) {
            float xv = b2f(xt[c * 434 + base]);
            #pragma unroll
            for (int t = 0; t < 9; t++) s[t] += xv * WsL[t * 64 + c];
        }
        float m = 0.f;
        #pragma unroll
        for (int t = 0; t < 9; t++) m += s[t];
        m *= (1.f / 9.f);
        float var = 0.f;
        #pragma unroll
        for (int t = 0; t < 9; t++) { float d = s[t] - m; var += d * d; }
        var *= (1.f / 8.f);                         // ddof=1
        float inv = 0.4714045207910317f / (sqrtf(var) + 1e-10f);  // STD_SPATIAL/(std+eps)
        #pragma unroll
        for (int t = 0; t < 9; t++) sfL[tid * 12 + t] = (s[t] - m) * inv;
    }
    __syncthreads();

    // ---- phase 3 v2: DDF + leaky relu, lane = channel, wave = row
    // Output pixels processed in even/odd pairs; 3x3 window kept in rolling
    // registers A..E per row (dword dw(n) covers halo px {2n, 2n+1}):
    //   pair kp (k0=2kp): even uses A=hi(dw kp+1), B=lo(dw kp+2), C=hi(dw kp+2)
    //                     odd  uses B, C, D=lo(dw kp+3)
    //   roll: A<-C, B<-D, C<-E, D/E <- unpack(dw kp+4)
    {
        int lane = tid & 63;               // channel
        int hl = tid >> 6;                 // row in tile
        float cfv[9];
        #pragma unroll
        for (int t = 0; t < 9; t++) cfv[t] = cfL[lane * 9 + t];
        const uint_t* lds32 = (const uint_t*)xt;
        int gh = h0 + hl;
        size_t yrow = ((size_t)b * HWD + (size_t)gh * WW + w0) * 64 + lane;

        int rbase[3];
        float A[3], Bw[3], Cw[3], Dw[3], Ew[3];
        #pragma unroll
        for (int r = 0; r < 3; r++) {
            rbase[r] = lane * 217 + (hl + r) * 36;
            uint_t d1 = lds32[rbase[r] + 1];
            uint_t d2 = lds32[rbase[r] + 2];
            uint_t d3 = lds32[rbase[r] + 3];
            A[r]  = b2f(d1 >> 16);
            Bw[r] = b2f(d2); Cw[r] = b2f(d2 >> 16);
            Dw[r] = b2f(d3); Ew[r] = b2f(d3 >> 16);
        }
        const float* sfrow = &sfL[hl * 64 * 12];
        #pragma unroll
        for (int kp = 0; kp < 32; kp++) {
            const float* sp0 = sfrow + kp * 24;
            const float* sp1 = sp0 + 12;
            float acc0 = 0.f, acc1 = 0.f;
            #pragma unroll
            for (int r = 0; r < 3; r++) {
                float w00 = cfv[r * 3 + 0] * sp0[r * 3 + 0];
                float w01 = cfv[r * 3 + 1] * sp0[r * 3 + 1];
                float w02 = cfv[r * 3 + 2] * sp0[r * 3 + 2];
                float w10 = cfv[r * 3 + 0] * sp1[r * 3 + 0];
                float w11 = cfv[r * 3 + 1] * sp1[r * 3 + 1];
                float w12 = cfv[r * 3 + 2] * sp1[r * 3 + 2];
                acc0 += A[r]  * w00 + Bw[r] * w01 + Cw[r] * w02;
                acc1 += Bw[r] * w10 + Cw[r] * w11 + Dw[r] * w12;
            }
            #pragma unroll
            for (int r = 0; r < 3; r++) {
                uint_t dn = lds32[rbase[r] + kp + 4];
                A[r] = Cw[r]; Bw[r] = Dw[r]; Cw[r] = Ew[r];
                Dw[r] = b2f(dn); Ew[r] = b2f(dn >> 16);
            }
            float v0 = acc0 >= 0.f ? acc0 : 0.1f * acc0;
            float v1 = acc1 >= 0.f ? acc1 : 0.1f * acc1;
            y[yrow + (size_t)(kp * 2) * 64]     = f2b(v0);
            y[yrow + (size_t)(kp * 2 + 1) * 64] = f2b(v1);
        }
    }
}

// ---------------- kernel 5 v3: 3x3 conv (MFMA) from LDS-staged y tile + bias + residual
#define CONV_LDS_BYTES (6 * 66 * 128)     // 50688

__global__ __launch_bounds__(256, 3)
void k_conv(const ushort_t* __restrict__ y, const ushort_t* __restrict__ wt,
            const float* __restrict__ x, const float* __restrict__ bc,
            float* __restrict__ out) {
    __shared__ char yt[CONV_LDS_BYTES];

    // 2304 blocks = 16 b x 48 ht x 3 wt ; bijective XCD swizzle (2304/8 = 288)
    int bid = blockIdx.x;
    int swz = (bid & 7) * 288 + (bid >> 3);
    int b = swz / 144;
    int rem = swz - b * 144;
    int ht = rem / 3;
    int wtile = rem - ht * 3;
    int h0 = ht * 4, w0 = wtile * 64;

    int tid = threadIdx.x;
    int lane = tid & 63, ln = lane & 15, quad = lane >> 4;
    int cb = (tid >> 6) * 16;              // wave's 16-co group

    // ---- stage y tile into LDS (once per block), swizzled
    const ushort_t* yb = y + (size_t)b * HWD * 64;
    #pragma unroll
    for (int j = 0; j < 13; j++) {
        int i = tid + j * 256;             // [0, 3168) chunks of 16B
        if (i < 6 * 66 * 8) {
            int row = i / 528;             // 528 = 66*8
            int r2 = i - row * 528;
            int p = r2 >> 3, c = r2 & 7;
            int gh = h0 - 1 + row, gw = w0 - 1 + p;
            uint4 v;
            if (gh >= 0 && gh < HH && gw >= 0 && gw < WW)
                v = *(const uint4*)(yb + ((size_t)(gh * WW + gw) * 64 + c * 8));
            else { v.x = 0; v.y = 0; v.z = 0; v.w = 0; }
            int off = ((row * 66 + p) << 7) + ((c ^ (p & 7)) << 4);
            *(uint4*)(yt + off) = v;
        }
    }

    // ---- weights (18 frags = 72 regs) + bias, loads overlap staging
    bf16x8 wf[9][2];
    #pragma unroll
    for (int t = 0; t < 9; t++)
        #pragma unroll
        for (int ks = 0; ks < 2; ks++)
            wf[t][ks] = ld8(wt + ((t * 64 + cb + ln) * 64 + ks * 32 + quad * 8));
    float bcv[4];
    #pragma unroll
    for (int r = 0; r < 4; r++)
        bcv[r] = bc[cb + quad * 4 + r];

    __syncthreads();

    // ---- compute: 4 out rows x 4 px strips per wave (16 co each)
    for (int orow = 0; orow < 4; orow++) {
        int gh = h0 + orow;
        #pragma unroll
        for (int s = 0; s < 4; s++) {
            // residual prefetch (latency hides under MFMA block below)
            size_t o0 = (size_t)(b * 64 + cb) * HWD + (size_t)gh * WW + w0 + s * 16 + ln;
            float xv[4];
            #pragma unroll
            for (int r = 0; r < 4; r++)
                xv[r] = x[o0 + (size_t)(quad * 4 + r) * HWD];

            f32x4 acc;
            acc[0] = bcv[0]; acc[1] = bcv[1]; acc[2] = bcv[2]; acc[3] = bcv[3];

            #pragma unroll
            for (int t = 0; t < 9; t++) {
                const int u_ = t / 3, v_ = t % 3;
                int p = s * 16 + ln + v_;                    // LDS px (halo coords)
                int boff = ((orow + u_) * 66 + p) << 7;
                int a0 = boff + ((quad ^ (p & 7)) << 4);     // ks=0 chunk slot
                int a1 = a0 ^ 64;                            // ks=1 flips chunk bit 2
                bf16x8 f0 = __builtin_bit_cast(bf16x8, *(const uint4*)(yt + a0));
                bf16x8 f1 = __builtin_bit_cast(bf16x8, *(const uint4*)(yt + a1));
                acc = __builtin_amdgcn_mfma_f32_16x16x32_bf16(wf[t][0], f0, acc, 0, 0, 0);
                acc = __builtin_amdgcn_mfma_f32_16x16x32_bf16(wf[t][1], f1, acc, 0, 0, 0);
            }

            #pragma unroll
            for (int r = 0; r < 4; r++)
                out[o0 + (size_t)(quad * 4 + r) * HWD] = acc[r] + xv[r];
        }
    }
}

extern "C" void kernel_launch(void* const* d_in, const int* in_sizes, int n_in,
                              void* d_out, int out_size, void* d_ws, size_t ws_size,
                              hipStream_t stream) {
    const float* x      = (const float*)d_in[0];
    const float* Ws     = (const float*)d_in[1];
    const float* bs     = (const float*)d_in[2];
    const float* W1     = (const float*)d_in[3];
    const float* b1     = (const float*)d_in[4];
    const float* W2     = (const float*)d_in[5];
    const float* b2     = (const float*)d_in[6];
    const float* std_ch = (const float*)d_in[7];
    const float* Wc     = (const float*)d_in[8];
    const float* bc     = (const float*)d_in[9];
    float* out = (float*)d_out;

    char* ws = (char*)d_ws;
    float*    pooled = (float*)(ws);                 // 4 KB
    float*    cf     = (float*)(ws + 4096);          // 36.9 KB
    ushort_t* wt     = (ushort_t*)(ws + 40960);      // 73.7 KB (ends 114688)
    ushort_t* y      = (ushort_t*)(ws + 131072);     // 75.5 MB

    k_prep<<<dim3(144), dim3(256), 0, stream>>>(Wc, wt);
    k_pool<<<dim3(64, 16), dim3(256), 0, stream>>>(x, pooled);
    k_mlp<<<dim3(16), dim3(64), 0, stream>>>(pooled, W1, b1, W2, b2, std_ch, cf);
    k_fused<<<dim3(144, 16), dim3(256), 0, stream>>>(x, Ws, bs, cf, y);
    k_conv<<<dim3(2304), dim3(256), 0, stream>>>(y, wt, x, bc, out);
}

// Round 4
// 513.260 us; speedup vs baseline: 1.0568x; 1.0568x over previous
//
#include <hip/hip_runtime.h>

typedef unsigned short ushort_t;
typedef unsigned int uint_t;

typedef __attribute__((ext_vector_type(8))) __bf16 bf16x8;
typedef __attribute__((ext_vector_type(4))) float f32x4;

#define HH 192
#define WW 192
#define HWD (192*192)          // 36864
#define CC 64
#define BB 16

__device__ __forceinline__ float b2f(uint_t u) {
    return __uint_as_float((u & 0xffffu) << 16);
}
__device__ __forceinline__ ushort_t f2b(float f) {
    uint_t x = __float_as_uint(f);
    uint_t r = x + 0x7fffu + ((x >> 16) & 1u);   // RNE fp32 -> bf16
    return (ushort_t)(r >> 16);
}
__device__ __forceinline__ bf16x8 zero8() {
    uint4 z; z.x = 0; z.y = 0; z.z = 0; z.w = 0;
    return __builtin_bit_cast(bf16x8, z);
}
__device__ __forceinline__ bf16x8 ld8(const ushort_t* p) {
    return __builtin_bit_cast(bf16x8, *(const uint4*)p);
}

// ---------------- kernel 1: Wc[co][ci][u][v] fp32 -> wt[t][co][ci] bf16
__global__ void k_prep(const float* __restrict__ Wc, ushort_t* __restrict__ wt) {
    int i = blockIdx.x * 256 + threadIdx.x;
    if (i < 9 * 64 * 64) {
        int t  = i >> 12;
        int co = (i >> 6) & 63;
        int ci = i & 63;
        wt[i] = f2b(Wc[(co * 64 + ci) * 9 + t]);
    }
}

// ---------------- kernel 2: pooled[b][c] = mean over H*W (fp32)
__global__ void k_pool(const float* __restrict__ x, float* __restrict__ pooled) {
    int c = blockIdx.x, b = blockIdx.y, tid = threadIdx.x;
    const float4* xp = (const float4*)(x + (size_t)(b * 64 + c) * HWD);
    float s = 0.f;
    for (int i = tid; i < HWD / 4; i += 256) {
        float4 u = xp[i];
        s += u.x + u.y + u.z + u.w;
    }
    __shared__ float red[4];
    for (int o = 32; o > 0; o >>= 1) s += __shfl_down(s, o, 64);
    if ((tid & 63) == 0) red[tid >> 6] = s;
    __syncthreads();
    if (tid == 0) pooled[b * 64 + c] = (red[0] + red[1] + red[2] + red[3]) * (1.f / (float)HWD);
}

// ---------------- kernel 3: MLP + channel filter norm -> cf[b][c][t] fp32
__global__ void k_mlp(const float* __restrict__ pooled,
                      const float* __restrict__ W1, const float* __restrict__ b1,
                      const float* __restrict__ W2, const float* __restrict__ b2,
                      const float* __restrict__ std_ch, float* __restrict__ cf) {
    int b = blockIdx.x, tid = threadIdx.x;  // 64 threads
    __shared__ float pl[64], hv[12];
    pl[tid] = pooled[b * 64 + tid];
    __syncthreads();
    if (tid < 12) {
        float h = b1[tid];
        for (int c = 0; c < 64; c++) h += pl[c] * W1[tid * 64 + c];
        hv[tid] = h > 0.f ? h : 0.f;
    }
    __syncthreads();
    int c = tid;
    float r[9]; float m = 0.f;
    #pragma unroll
    for (int t = 0; t < 9; t++) {
        float v = b2[c * 9 + t];
        #pragma unroll
        for (int k = 0; k < 12; k++) v += hv[k] * W2[(c * 9 + t) * 12 + k];
        r[t] = v; m += v;
    }
    m *= (1.f / 9.f);
    float var = 0.f;
    #pragma unroll
    for (int t = 0; t < 9; t++) { float d = r[t] - m; var += d * d; }
    var *= (1.f / 8.f);                     // ddof=1
    float inv = 1.f / (sqrtf(var) + 1e-10f);
    #pragma unroll
    for (int t = 0; t < 9; t++)
        cf[(b * 64 + c) * 9 + t] = (r[t] - m) * inv * std_ch[c * 9 + t];
}

// ---------------- kernel 4: FUSED sf + DDF + leaky -> y NHWC bf16
// Phase 3 v3: pair-parity (no cndmask) + rolling window regs, CONTAINED:
//   f32x4 sf loads (as in v1) + #pragma unroll 4 (v2's full unroll spilled
//   ~300B/thread to scratch: WRITE_SIZE 74->249MB. Keep live ranges short.)
__global__ __launch_bounds__(256, 2)
void k_fused(const float* __restrict__ x, const float* __restrict__ Ws,
             const float* __restrict__ bs, const float* __restrict__ cf,
             ushort_t* __restrict__ y) {
    __shared__ ushort_t xt[64 * 434];      // 55.5 KB
    __shared__ float sfL[256 * 12];        // 12.3 KB
    __shared__ float WsL[576];
    __shared__ float cfL[576];
    __shared__ float bsL[9];

    int b = blockIdx.y;
    int tw = blockIdx.x % 3, th = blockIdx.x / 3;
    int h0 = th * 4, w0 = tw * 64;
    int tid = threadIdx.x;

    for (int i = tid; i < 576; i += 256) { WsL[i] = Ws[i]; cfL[i] = cf[b * 576 + i]; }
    if (tid < 9) bsL[tid] = bs[tid];

    // ---- phase 1: stage x tile (+halo) as bf16 into LDS
    const float* xb = x + (size_t)b * 64 * HWD;
    #pragma unroll
    for (int j = 0; j < 27; j++) {
        int idx = tid + j * 256;           // [0, 6912)
        int c = idx / 108;
        int rem = idx - c * 108;
        int r = rem / 18, seg = rem - r * 18;
        int gr = h0 - 1 + r;
        int gw0 = w0 - 4 + seg * 4;        // float4-aligned; fully in or out of [0,192)
        float4 v;
        if (gr >= 0 && gr < HH && gw0 >= 0 && gw0 < WW)
            v = *(const float4*)(xb + (size_t)c * HWD + (size_t)gr * WW + gw0);
        else { v.x = 0.f; v.y = 0.f; v.z = 0.f; v.w = 0.f; }
        int o = c * 434 + r * 72 + seg * 4;         // even -> 4B aligned
        *(uint_t*)(&xt[o])     = (uint_t)f2b(v.x) | ((uint_t)f2b(v.y) << 16);
        *(uint_t*)(&xt[o + 2]) = (uint_t)f2b(v.z) | ((uint_t)f2b(v.w) << 16);
    }
    __syncthreads();

    // ---- phase 2: spatial filter for own pixel
    {
        int hl = tid >> 6, wl = tid & 63;
        float s[9];
        #pragma unroll
        for (int t = 0; t < 9; t++) s[t] = bsL[t];
        int base = (hl + 1) * 72 + wl + 4;          // center pixel in halo coords
        for (int c = 0; c < 64; c++) {
            float xv = b2f(xt[c * 434 + base]);
            #pragma unroll
            for (int t = 0; t < 9; t++) s[t] += xv * WsL[t * 64 + c];
        }
        float m = 0.f;
        #pragma unroll
        for (int t = 0; t < 9; t++) m += s[t];
        m *= (1.f / 9.f);
        float var = 0.f;
        #pragma unroll
        for (int t = 0; t < 9; t++) { float d = s[t] - m; var += d * d; }
        var *= (1.f / 8.f);                         // ddof=1
        float inv = 0.4714045207910317f / (sqrtf(var) + 1e-10f);  // STD_SPATIAL/(std+eps)
        #pragma unroll
        for (int t = 0; t < 9; t++) sfL[tid * 12 + t] = (s[t] - m) * inv;
    }
    __syncthreads();

    // ---- phase 3 v3: DDF + leaky relu, lane = channel, wave = row
    // Even/odd pixel pairs; 3x3 window in rolling regs A..E per row
    // (dword dw(n) covers halo px {2n, 2n+1}):
    //   pair kp (k0=2kp): even uses A=hi(dw kp+1), B=lo(dw kp+2), C=hi(dw kp+2)
    //                     odd  uses B, C, D=lo(dw kp+3)
    //   roll: A<-C, B<-D, C<-E, D/E <- unpack(dw kp+4)
    {
        int lane = tid & 63;               // channel
        int hl = tid >> 6;                 // row in tile
        float cfv[9];
        #pragma unroll
        for (int t = 0; t < 9; t++) cfv[t] = cfL[lane * 9 + t];
        const uint_t* lds32 = (const uint_t*)xt;
        int gh = h0 + hl;
        size_t yrow = ((size_t)b * HWD + (size_t)gh * WW + w0) * 64 + lane;

        int rbase[3];
        float A[3], Bw[3], Cw[3], Dw[3], Ew[3];
        #pragma unroll
        for (int r = 0; r < 3; r++) {
            rbase[r] = lane * 217 + (hl + r) * 36;
            uint_t d1 = lds32[rbase[r] + 1];
            uint_t d2 = lds32[rbase[r] + 2];
            uint_t d3 = lds32[rbase[r] + 3];
            A[r]  = b2f(d1 >> 16);
            Bw[r] = b2f(d2); Cw[r] = b2f(d2 >> 16);
            Dw[r] = b2f(d3); Ew[r] = b2f(d3 >> 16);
        }
        const float* sfrow = &sfL[hl * 64 * 12];
        #pragma unroll 4
        for (int kp = 0; kp < 32; kp++) {
            const f32x4* sp0 = (const f32x4*)(sfrow + kp * 24);
            f32x4 s00 = sp0[0], s01 = sp0[1];
            float s08 = sfrow[kp * 24 + 8];
            const f32x4* sp1 = (const f32x4*)(sfrow + kp * 24 + 12);
            f32x4 s10 = sp1[0], s11 = sp1[1];
            float s18 = sfrow[kp * 24 + 20];

            float acc0, acc1;
            {
                float w0_ = cfv[0] * s00[0], w1_ = cfv[1] * s00[1], w2_ = cfv[2] * s00[2];
                float w3_ = cfv[3] * s00[3], w4_ = cfv[4] * s01[0], w5_ = cfv[5] * s01[1];
                float w6_ = cfv[6] * s01[2], w7_ = cfv[7] * s01[3], w8_ = cfv[8] * s08;
                acc0 = A[0] * w0_ + Bw[0] * w1_ + Cw[0] * w2_
                     + A[1] * w3_ + Bw[1] * w4_ + Cw[1] * w5_
                     + A[2] * w6_ + Bw[2] * w7_ + Cw[2] * w8_;
            }
            {
                float w0_ = cfv[0] * s10[0], w1_ = cfv[1] * s10[1], w2_ = cfv[2] * s10[2];
                float w3_ = cfv[3] * s10[3], w4_ = cfv[4] * s11[0], w5_ = cfv[5] * s11[1];
                float w6_ = cfv[6] * s11[2], w7_ = cfv[7] * s11[3], w8_ = cfv[8] * s18;
                acc1 = Bw[0] * w0_ + Cw[0] * w1_ + Dw[0] * w2_
                     + Bw[1] * w3_ + Cw[1] * w4_ + Dw[1] * w5_
                     + Bw[2] * w6_ + Cw[2] * w7_ + Dw[2] * w8_;
            }
            #pragma unroll
            for (int r = 0; r < 3; r++) {
                uint_t dn = lds32[rbase[r] + kp + 4];
                A[r] = Cw[r]; Bw[r] = Dw[r]; Cw[r] = Ew[r];
                Dw[r] = b2f(dn); Ew[r] = b2f(dn >> 16);
            }
            float v0 = acc0 >= 0.f ? acc0 : 0.1f * acc0;
            float v1 = acc1 >= 0.f ? acc1 : 0.1f * acc1;
            y[yrow + (size_t)(kp * 2) * 64]     = f2b(v0);
            y[yrow + (size_t)(kp * 2 + 1) * 64] = f2b(v1);
        }
    }
}

// ---------------- kernel 5 v3: 3x3 conv (MFMA) from LDS-staged y tile + bias + residual
#define CONV_LDS_BYTES (6 * 66 * 128)     // 50688

__global__ __launch_bounds__(256, 3)
void k_conv(const ushort_t* __restrict__ y, const ushort_t* __restrict__ wt,
            const float* __restrict__ x, const float* __restrict__ bc,
            float* __restrict__ out) {
    __shared__ char yt[CONV_LDS_BYTES];

    // 2304 blocks = 16 b x 48 ht x 3 wt ; bijective XCD swizzle (2304/8 = 288)
    int bid = blockIdx.x;
    int swz = (bid & 7) * 288 + (bid >> 3);
    int b = swz / 144;
    int rem = swz - b * 144;
    int ht = rem / 3;
    int wtile = rem - ht * 3;
    int h0 = ht * 4, w0 = wtile * 64;

    int tid = threadIdx.x;
    int lane = tid & 63, ln = lane & 15, quad = lane >> 4;
    int cb = (tid >> 6) * 16;              // wave's 16-co group

    // ---- stage y tile into LDS (once per block), swizzled
    const ushort_t* yb = y + (size_t)b * HWD * 64;
    #pragma unroll
    for (int j = 0; j < 13; j++) {
        int i = tid + j * 256;             // [0, 3168) chunks of 16B
        if (i < 6 * 66 * 8) {
            int row = i / 528;             // 528 = 66*8
            int r2 = i - row * 528;
            int p = r2 >> 3, c = r2 & 7;
            int gh = h0 - 1 + row, gw = w0 - 1 + p;
            uint4 v;
            if (gh >= 0 && gh < HH && gw >= 0 && gw < WW)
                v = *(const uint4*)(yb + ((size_t)(gh * WW + gw) * 64 + c * 8));
            else { v.x = 0; v.y = 0; v.z = 0; v.w = 0; }
            int off = ((row * 66 + p) << 7) + ((c ^ (p & 7)) << 4);
            *(uint4*)(yt + off) = v;
        }
    }

    // ---- weights (18 frags = 72 regs) + bias, loads overlap staging
    bf16x8 wf[9][2];
    #pragma unroll
    for (int t = 0; t < 9; t++)
        #pragma unroll
        for (int ks = 0; ks < 2; ks++)
            wf[t][ks] = ld8(wt + ((t * 64 + cb + ln) * 64 + ks * 32 + quad * 8));
    float bcv[4];
    #pragma unroll
    for (int r = 0; r < 4; r++)
        bcv[r] = bc[cb + quad * 4 + r];

    __syncthreads();

    // ---- compute: 4 out rows x 4 px strips per wave (16 co each)
    for (int orow = 0; orow < 4; orow++) {
        int gh = h0 + orow;
        #pragma unroll
        for (int s = 0; s < 4; s++) {
            // residual prefetch (latency hides under MFMA block below)
            size_t o0 = (size_t)(b * 64 + cb) * HWD + (size_t)gh * WW + w0 + s * 16 + ln;
            float xv[4];
            #pragma unroll
            for (int r = 0; r < 4; r++)
                xv[r] = x[o0 + (size_t)(quad * 4 + r) * HWD];

            f32x4 acc;
            acc[0] = bcv[0]; acc[1] = bcv[1]; acc[2] = bcv[2]; acc[3] = bcv[3];

            #pragma unroll
            for (int t = 0; t < 9; t++) {
                const int u_ = t / 3, v_ = t % 3;
                int p = s * 16 + ln + v_;                    // LDS px (halo coords)
                int boff = ((orow + u_) * 66 + p) << 7;
                int a0 = boff + ((quad ^ (p & 7)) << 4);     // ks=0 chunk slot
                int a1 = a0 ^ 64;                            // ks=1 flips chunk bit 2
                bf16x8 f0 = __builtin_bit_cast(bf16x8, *(const uint4*)(yt + a0));
                bf16x8 f1 = __builtin_bit_cast(bf16x8, *(const uint4*)(yt + a1));
                acc = __builtin_amdgcn_mfma_f32_16x16x32_bf16(wf[t][0], f0, acc, 0, 0, 0);
                acc = __builtin_amdgcn_mfma_f32_16x16x32_bf16(wf[t][1], f1, acc, 0, 0, 0);
            }

            #pragma unroll
            for (int r = 0; r < 4; r++)
                out[o0 + (size_t)(quad * 4 + r) * HWD] = acc[r] + xv[r];
        }
    }
}

extern "C" void kernel_launch(void* const* d_in, const int* in_sizes, int n_in,
                              void* d_out, int out_size, void* d_ws, size_t ws_size,
                              hipStream_t stream) {
    const float* x      = (const float*)d_in[0];
    const float* Ws     = (const float*)d_in[1];
    const float* bs     = (const float*)d_in[2];
    const float* W1     = (const float*)d_in[3];
    const float* b1     = (const float*)d_in[4];
    const float* W2     = (const float*)d_in[5];
    const float* b2     = (const float*)d_in[6];
    const float* std_ch = (const float*)d_in[7];
    const float* Wc     = (const float*)d_in[8];
    const float* bc     = (const float*)d_in[9];
    float* out = (float*)d_out;

    char* ws = (char*)d_ws;
    float*    pooled = (float*)(ws);                 // 4 KB
    float*    cf     = (float*)(ws + 4096);          // 36.9 KB
    ushort_t* wt     = (ushort_t*)(ws + 40960);      // 73.7 KB (ends 114688)
    ushort_t* y      = (ushort_t*)(ws + 131072);     // 75.5 MB

    k_prep<<<dim3(144), dim3(256), 0, stream>>>(Wc, wt);
    k_pool<<<dim3(64, 16), dim3(256), 0, stream>>>(x, pooled);
    k_mlp<<<dim3(16), dim3(64), 0, stream>>>(pooled, W1, b1, W2, b2, std_ch, cf);
    k_fused<<<dim3(144, 16), dim3(256), 0, stream>>>(x, Ws, bs, cf, y);
    k_conv<<<dim3(2304), dim3(256), 0, stream>>>(y, wt, x, bc, out);
}

// Round 5
// 495.742 us; speedup vs baseline: 1.0942x; 1.0353x over previous
//
#include <hip/hip_runtime.h>

typedef unsigned short ushort_t;
typedef unsigned int uint_t;

typedef __attribute__((ext_vector_type(8))) __bf16 bf16x8;
typedef __attribute__((ext_vector_type(4))) float f32x4;

#define HH 192
#define WW 192
#define HWD (192*192)          // 36864
#define CC 64
#define BB 16

__device__ __forceinline__ float b2f(uint_t u) {
    return __uint_as_float((u & 0xffffu) << 16);
}
__device__ __forceinline__ ushort_t f2b(float f) {
    uint_t x = __float_as_uint(f);
    uint_t r = x + 0x7fffu + ((x >> 16) & 1u);   // RNE fp32 -> bf16
    return (ushort_t)(r >> 16);
}
__device__ __forceinline__ bf16x8 zero8() {
    uint4 z; z.x = 0; z.y = 0; z.z = 0; z.w = 0;
    return __builtin_bit_cast(bf16x8, z);
}
__device__ __forceinline__ bf16x8 ld8(const ushort_t* p) {
    return __builtin_bit_cast(bf16x8, *(const uint4*)p);
}

// ---------------- kernel 1: Wc[co][ci][u][v] fp32 -> wt[t][co][ci] bf16
__global__ void k_prep(const float* __restrict__ Wc, ushort_t* __restrict__ wt) {
    int i = blockIdx.x * 256 + threadIdx.x;
    if (i < 9 * 64 * 64) {
        int t  = i >> 12;
        int co = (i >> 6) & 63;
        int ci = i & 63;
        wt[i] = f2b(Wc[(co * 64 + ci) * 9 + t]);
    }
}

// ---------------- kernel 2: pooled[b][c] = mean over H*W (fp32)
__global__ void k_pool(const float* __restrict__ x, float* __restrict__ pooled) {
    int c = blockIdx.x, b = blockIdx.y, tid = threadIdx.x;
    const float4* xp = (const float4*)(x + (size_t)(b * 64 + c) * HWD);
    float s = 0.f;
    for (int i = tid; i < HWD / 4; i += 256) {
        float4 u = xp[i];
        s += u.x + u.y + u.z + u.w;
    }
    __shared__ float red[4];
    for (int o = 32; o > 0; o >>= 1) s += __shfl_down(s, o, 64);
    if ((tid & 63) == 0) red[tid >> 6] = s;
    __syncthreads();
    if (tid == 0) pooled[b * 64 + c] = (red[0] + red[1] + red[2] + red[3]) * (1.f / (float)HWD);
}

// ---------------- kernel 3: MLP + channel filter norm -> cf[b][c][t] fp32
__global__ void k_mlp(const float* __restrict__ pooled,
                      const float* __restrict__ W1, const float* __restrict__ b1,
                      const float* __restrict__ W2, const float* __restrict__ b2,
                      const float* __restrict__ std_ch, float* __restrict__ cf) {
    int b = blockIdx.x, tid = threadIdx.x;  // 64 threads
    __shared__ float pl[64], hv[12];
    pl[tid] = pooled[b * 64 + tid];
    __syncthreads();
    if (tid < 12) {
        float h = b1[tid];
        for (int c = 0; c < 64; c++) h += pl[c] * W1[tid * 64 + c];
        hv[tid] = h > 0.f ? h : 0.f;
    }
    __syncthreads();
    int c = tid;
    float r[9]; float m = 0.f;
    #pragma unroll
    for (int t = 0; t < 9; t++) {
        float v = b2[c * 9 + t];
        #pragma unroll
        for (int k = 0; k < 12; k++) v += hv[k] * W2[(c * 9 + t) * 12 + k];
        r[t] = v; m += v;
    }
    m *= (1.f / 9.f);
    float var = 0.f;
    #pragma unroll
    for (int t = 0; t < 9; t++) { float d = r[t] - m; var += d * d; }
    var *= (1.f / 8.f);                     // ddof=1
    float inv = 1.f / (sqrtf(var) + 1e-10f);
    #pragma unroll
    for (int t = 0; t < 9; t++)
        cf[(b * 64 + c) * 9 + t] = (r[t] - m) * inv * std_ch[c * 9 + t];
}

// ---------------- kernel 4: FUSED sf + DDF + leaky -> y NHWC bf16
// Phase 3 = round-2 form (measured 128.6 us). Rolling-window/pair-parity
// rewrites regressed twice (loop-carried dep chain kills cross-k ILP).
__global__ __launch_bounds__(256, 2)
void k_fused(const float* __restrict__ x, const float* __restrict__ Ws,
             const float* __restrict__ bs, const float* __restrict__ cf,
             ushort_t* __restrict__ y) {
    __shared__ ushort_t xt[64 * 434];      // 55.5 KB
    __shared__ float sfL[256 * 12];        // 12.3 KB
    __shared__ float WsL[576];
    __shared__ float cfL[576];
    __shared__ float bsL[9];

    int b = blockIdx.y;
    int tw = blockIdx.x % 3, th = blockIdx.x / 3;
    int h0 = th * 4, w0 = tw * 64;
    int tid = threadIdx.x;

    for (int i = tid; i < 576; i += 256) { WsL[i] = Ws[i]; cfL[i] = cf[b * 576 + i]; }
    if (tid < 9) bsL[tid] = bs[tid];

    // ---- phase 1: stage x tile (+halo) as bf16 into LDS
    const float* xb = x + (size_t)b * 64 * HWD;
    #pragma unroll
    for (int j = 0; j < 27; j++) {
        int idx = tid + j * 256;           // [0, 6912)
        int c = idx / 108;
        int rem = idx - c * 108;
        int r = rem / 18, seg = rem - r * 18;
        int gr = h0 - 1 + r;
        int gw0 = w0 - 4 + seg * 4;        // float4-aligned; fully in or out of [0,192)
        float4 v;
        if (gr >= 0 && gr < HH && gw0 >= 0 && gw0 < WW)
            v = *(const float4*)(xb + (size_t)c * HWD + (size_t)gr * WW + gw0);
        else { v.x = 0.f; v.y = 0.f; v.z = 0.f; v.w = 0.f; }
        int o = c * 434 + r * 72 + seg * 4;         // even -> 4B aligned
        *(uint_t*)(&xt[o])     = (uint_t)f2b(v.x) | ((uint_t)f2b(v.y) << 16);
        *(uint_t*)(&xt[o + 2]) = (uint_t)f2b(v.z) | ((uint_t)f2b(v.w) << 16);
    }
    __syncthreads();

    // ---- phase 2: spatial filter for own pixel
    {
        int hl = tid >> 6, wl = tid & 63;
        float s[9];
        #pragma unroll
        for (int t = 0; t < 9; t++) s[t] = bsL[t];
        int base = (hl + 1) * 72 + wl + 4;          // center pixel in halo coords
        for (int c = 0; c < 64; c++) {
            float xv = b2f(xt[c * 434 + base]);
            #pragma unroll
            for (int t = 0; t < 9; t++) s[t] += xv * WsL[t * 64 + c];
        }
        float m = 0.f;
        #pragma unroll
        for (int t = 0; t < 9; t++) m += s[t];
        m *= (1.f / 9.f);
        float var = 0.f;
        #pragma unroll
        for (int t = 0; t < 9; t++) { float d = s[t] - m; var += d * d; }
        var *= (1.f / 8.f);                         // ddof=1
        float inv = 0.4714045207910317f / (sqrtf(var) + 1e-10f);  // STD_SPATIAL/(std+eps)
        #pragma unroll
        for (int t = 0; t < 9; t++) sfL[tid * 12 + t] = (s[t] - m) * inv;
    }
    __syncthreads();

    // ---- phase 3: DDF + leaky relu, lane = channel, wave = row (round-2 form)
    int lane = tid & 63;                   // channel
    int hl = tid >> 6;                     // row in tile
    float cfv[9];
    #pragma unroll
    for (int t = 0; t < 9; t++) cfv[t] = cfL[lane * 9 + t];
    const uint_t* lds32 = (const uint_t*)xt;
    int gh = h0 + hl;
    size_t yrow = ((size_t)b * HWD + (size_t)gh * WW + w0) * 64 + lane;

    for (int k = 0; k < 64; k++) {
        const f32x4* sp = (const f32x4*)&sfL[(hl * 64 + k) * 12];
        f32x4 s0 = sp[0], s1 = sp[1];
        float s8 = sfL[(hl * 64 + k) * 12 + 8];
        float wv[9];
        wv[0] = cfv[0] * s0[0]; wv[1] = cfv[1] * s0[1]; wv[2] = cfv[2] * s0[2];
        wv[3] = cfv[3] * s0[3]; wv[4] = cfv[4] * s1[0]; wv[5] = cfv[5] * s1[1];
        wv[6] = cfv[6] * s1[2]; wv[7] = cfv[7] * s1[3]; wv[8] = cfv[8] * s8;

        int p0 = k + 3;                    // first needed wh (window wl+3..wl+5)
        int a = p0 & ~1;
        bool odd = (p0 & 1) != 0;
        float acc = 0.f;
        #pragma unroll
        for (int r = 0; r < 3; r++) {
            int di = lane * 217 + (hl + r) * 36 + (a >> 1);
            uint_t d0 = lds32[di], d1 = lds32[di + 1];
            float v0 = b2f(d0), v1 = b2f(d0 >> 16), v2 = b2f(d1), v3 = b2f(d1 >> 16);
            float xa = odd ? v1 : v0;
            float xm = odd ? v2 : v1;
            float xc = odd ? v3 : v2;
            acc += xa * wv[r * 3 + 0] + xm * wv[r * 3 + 1] + xc * wv[r * 3 + 2];
        }
        float v = acc >= 0.f ? acc : 0.1f * acc;    // leaky BEFORE conv
        y[yrow + (size_t)k * 64] = f2b(v);
    }
}

// ---------------- kernel 5 v4: 3x3 conv (MFMA) from LDS-staged y tile + bias + residual
// Wave layout: phi = w&1 -> co half (32 co via 2 mt-tiles), rp = w>>1 -> rows {2rp,2rp+1}.
// Key change vs v3: B-fragment 2x reuse restored (each f0/f1 feeds 2 co-tiles ->
// LDS traffic halved) WITHOUT the 144-reg weight array: weights cycled per-t
// (wf[2][2] = 16 regs live, reloaded from L2-hot wt inside `#pragma unroll 1`
// t-loop; the 16 independent ds_read_b128 per t cover the reload latency).
// acc[2][4][2] = 64 VGPR; total ~150 -> 3 blocks/CU (LDS 50.7 KB also allows 3).
#define CONV_LDS_BYTES (6 * 66 * 128)     // 50688

__global__ __launch_bounds__(256, 3)
void k_conv(const ushort_t* __restrict__ y, const ushort_t* __restrict__ wt,
            const float* __restrict__ x, const float* __restrict__ bc,
            float* __restrict__ out) {
    __shared__ char yt[CONV_LDS_BYTES];

    // 2304 blocks = 16 b x 48 ht x 3 wt ; bijective XCD swizzle (2304/8 = 288)
    int bid = blockIdx.x;
    int swz = (bid & 7) * 288 + (bid >> 3);
    int b = swz / 144;
    int rem = swz - b * 144;
    int ht = rem / 3;
    int wtile = rem - ht * 3;
    int h0 = ht * 4, w0 = wtile * 64;

    int tid = threadIdx.x;
    int lane = tid & 63, ln = lane & 15, quad = lane >> 4;
    int wv_ = tid >> 6, phi = wv_ & 1, rp = wv_ >> 1;

    // ---- stage y tile into LDS (once per block), swizzled
    const ushort_t* yb = y + (size_t)b * HWD * 64;
    #pragma unroll
    for (int j = 0; j < 13; j++) {
        int i = tid + j * 256;             // [0, 3168) chunks of 16B
        if (i < 6 * 66 * 8) {
            int row = i / 528;             // 528 = 66*8
            int r2 = i - row * 528;
            int p = r2 >> 3, c = r2 & 7;
            int gh = h0 - 1 + row, gw = w0 - 1 + p;
            uint4 v;
            if (gh >= 0 && gh < HH && gw >= 0 && gw < WW)
                v = *(const uint4*)(yb + ((size_t)(gh * WW + gw) * 64 + c * 8));
            else { v.x = 0; v.y = 0; v.z = 0; v.w = 0; }
            int off = ((row * 66 + p) << 7) + ((c ^ (p & 7)) << 4);
            *(uint4*)(yt + off) = v;
        }
    }

    float bcv[2][4];
    #pragma unroll
    for (int mt = 0; mt < 2; mt++)
        #pragma unroll
        for (int r = 0; r < 4; r++)
            bcv[mt][r] = bc[phi * 32 + mt * 16 + quad * 4 + r];

    __syncthreads();

    // ---- accumulators: 2 rows x 4 strips x 2 co-tiles, init with bias
    f32x4 acc[2][4][2];
    #pragma unroll
    for (int row = 0; row < 2; row++)
        #pragma unroll
        for (int s = 0; s < 4; s++)
            #pragma unroll
            for (int mt = 0; mt < 2; mt++) {
                acc[row][s][mt][0] = bcv[mt][0]; acc[row][s][mt][1] = bcv[mt][1];
                acc[row][s][mt][2] = bcv[mt][2]; acc[row][s][mt][3] = bcv[mt][3];
            }

    // ---- t-cycled weights: 4 frags live (16 regs), unroll 1 stops hoisting
    #pragma unroll 1
    for (int t = 0; t < 9; t++) {
        bf16x8 wf00 = ld8(wt + ((t * 64 + phi * 32 + ln) * 64      + quad * 8));        // mt0 ks0
        bf16x8 wf01 = ld8(wt + ((t * 64 + phi * 32 + ln) * 64 + 32 + quad * 8));        // mt0 ks1
        bf16x8 wf10 = ld8(wt + ((t * 64 + phi * 32 + 16 + ln) * 64      + quad * 8));   // mt1 ks0
        bf16x8 wf11 = ld8(wt + ((t * 64 + phi * 32 + 16 + ln) * 64 + 32 + quad * 8));   // mt1 ks1
        int u_ = t / 3, v_ = t % 3;        // uniform (SALU magic-mul)
        #pragma unroll
        for (int row = 0; row < 2; row++) {
            int ra = rp * 2 + row + u_;    // staged row index, 0..5
            #pragma unroll
            for (int s = 0; s < 4; s++) {
                int p = s * 16 + ln + v_;                    // LDS px (halo coords)
                int a0 = ((ra * 66 + p) << 7) + ((quad ^ (p & 7)) << 4);
                bf16x8 f0 = __builtin_bit_cast(bf16x8, *(const uint4*)(yt + a0));
                bf16x8 f1 = __builtin_bit_cast(bf16x8, *(const uint4*)(yt + (a0 ^ 64)));
                acc[row][s][0] = __builtin_amdgcn_mfma_f32_16x16x32_bf16(wf00, f0, acc[row][s][0], 0, 0, 0);
                acc[row][s][1] = __builtin_amdgcn_mfma_f32_16x16x32_bf16(wf10, f0, acc[row][s][1], 0, 0, 0);
                acc[row][s][0] = __builtin_amdgcn_mfma_f32_16x16x32_bf16(wf01, f1, acc[row][s][0], 0, 0, 0);
                acc[row][s][1] = __builtin_amdgcn_mfma_f32_16x16x32_bf16(wf11, f1, acc[row][s][1], 0, 0, 0);
            }
        }
    }

    // ---- epilogue: residual add + store
    #pragma unroll
    for (int row = 0; row < 2; row++) {
        int gh = h0 + rp * 2 + row;
        #pragma unroll
        for (int s = 0; s < 4; s++) {
            #pragma unroll
            for (int mt = 0; mt < 2; mt++) {
                size_t o0 = (size_t)(b * 64 + phi * 32 + mt * 16) * HWD
                          + (size_t)gh * WW + w0 + s * 16 + ln;
                float xv[4];
                #pragma unroll
                for (int r = 0; r < 4; r++)
                    xv[r] = x[o0 + (size_t)(quad * 4 + r) * HWD];
                #pragma unroll
                for (int r = 0; r < 4; r++)
                    out[o0 + (size_t)(quad * 4 + r) * HWD] = acc[row][s][mt][r] + xv[r];
            }
        }
    }
}

extern "C" void kernel_launch(void* const* d_in, const int* in_sizes, int n_in,
                              void* d_out, int out_size, void* d_ws, size_t ws_size,
                              hipStream_t stream) {
    const float* x      = (const float*)d_in[0];
    const float* Ws     = (const float*)d_in[1];
    const float* bs     = (const float*)d_in[2];
    const float* W1     = (const float*)d_in[3];
    const float* b1     = (const float*)d_in[4];
    const float* W2     = (const float*)d_in[5];
    const float* b2     = (const float*)d_in[6];
    const float* std_ch = (const float*)d_in[7];
    const float* Wc     = (const float*)d_in[8];
    const float* bc     = (const float*)d_in[9];
    float* out = (float*)d_out;

    char* ws = (char*)d_ws;
    float*    pooled = (float*)(ws);                 // 4 KB
    float*    cf     = (float*)(ws + 4096);          // 36.9 KB
    ushort_t* wt     = (ushort_t*)(ws + 40960);      // 73.7 KB (ends 114688)
    ushort_t* y      = (ushort_t*)(ws + 131072);     // 75.5 MB

    k_prep<<<dim3(144), dim3(256), 0, stream>>>(Wc, wt);
    k_pool<<<dim3(64, 16), dim3(256), 0, stream>>>(x, pooled);
    k_mlp<<<dim3(16), dim3(64), 0, stream>>>(pooled, W1, b1, W2, b2, std_ch, cf);
    k_fused<<<dim3(144, 16), dim3(256), 0, stream>>>(x, Ws, bs, cf, y);
    k_conv<<<dim3(2304), dim3(256), 0, stream>>>(y, wt, x, bc, out);
}